// Round 1
// baseline (6089.272 us; speedup 1.0000x reference)
//
#include <hip/hip_runtime.h>
#include <cstddef>

typedef unsigned short u16;
typedef __bf16 bf16x8 __attribute__((ext_vector_type(8)));
typedef float f32x4 __attribute__((ext_vector_type(4)));

__device__ __forceinline__ u16 f2b(float f) {
    unsigned u = __float_as_uint(f);
    u += 0x7fffu + ((u >> 16) & 1u);          // round-to-nearest-even
    return (u16)(u >> 16);
}
__device__ __forceinline__ float b2f(u16 h) { return __uint_as_float(((unsigned)h) << 16); }

__device__ __forceinline__ f32x4 mfma16(bf16x8 a, bf16x8 b, f32x4 c) {
    return __builtin_amdgcn_mfma_f32_16x16x32_bf16(a, b, c, 0, 0, 0);
}

// ---------------------------------------------------------------------------
// constants
// ---------------------------------------------------------------------------
// B=256, S=512, D=128, H=256, HH=128, L=64.  chunk = 128 steps, 4 chunks.
#define CH   128
#define NCH  4
#define MCH  (CH * 256)   // rows per chunk = 32768

// ---------------------------------------------------------------------------
// pack: W [N][K] f32  ->  MFMA B-fragments bf16, frag f=(nt*KT+kt): 64 lanes x 8
//   B[k][n] = W[n][k],  n = nt*16 + (lane&15),  k = kt*32 + (lane>>4)*8 + j
// ---------------------------------------------------------------------------
__global__ __launch_bounds__(64) void pack_kernel(const float* __restrict__ W,
                                                  u16* __restrict__ out, int K) {
    int f = blockIdx.x, lane = threadIdx.x, q = lane >> 4, ln = lane & 15;
    int KT = K / 32;
    int nt = f / KT, kt = f % KT;
    int n = nt * 16 + ln;
    int kb = kt * 32 + q * 8;
#pragma unroll
    for (int j = 0; j < 8; j++)
        out[((size_t)f * 64 + lane) * 8 + j] = f2b(W[(size_t)n * K + kb + j]);
}

// ---------------------------------------------------------------------------
__global__ void zero_kernel(float* __restrict__ st, float* __restrict__ lossslot) {
    int i = blockIdx.x * 256 + threadIdx.x;
    if (i < 196608) st[i] = 0.f;
    if (i == 0) *lossslot = 0.f;
}

// emb[row=t*256+b][d] = path[tok0][d] + sys[tok1][d]   (bf16)
__global__ __launch_bounds__(128) void embed_kernel(const int* __restrict__ tok,
                                                    const float* __restrict__ pw,
                                                    const float* __restrict__ sw,
                                                    u16* __restrict__ emb) {
    int r = blockIdx.x;          // row = t*256 + b
    int b = r & 255, t = r >> 8;
    const int* tp = tok + ((size_t)b * 512 + t) * 2;
    int p = tp[0], s = tp[1];
    float v = pw[(size_t)p * 128 + threadIdx.x] + sw[(size_t)s * 128 + threadIdx.x];
    emb[(size_t)r * 128 + threadIdx.x] = f2b(v);
}

// ---------------------------------------------------------------------------
// big GEMM: out[M=32768][N] = X[M][K](bf16) @ W.T + bias, W pre-packed frags.
// grid 512 x 256thr. Each WG stages half of W's fragments (98KB) in LDS.
// ---------------------------------------------------------------------------
template <int K, int N>
__global__ __launch_bounds__(256) void gemm_kernel(const u16* __restrict__ X,
                                                   const u16* __restrict__ Wp,
                                                   const float* __restrict__ bias,
                                                   u16* __restrict__ out) {
    constexpr int NH = N / 2, KT = K / 32, NTL = NH / 16;
    __shared__ u16 wl[NH * K];
    int tid = threadIdx.x, wid = tid >> 6, lane = tid & 63, q = lane >> 4, ln = lane & 15;
    int half = blockIdx.x & 1, mg = blockIdx.x >> 1;
    {
        const bf16x8* src = (const bf16x8*)(Wp + (size_t)half * NH * K);
        bf16x8* dst = (bf16x8*)wl;
#pragma unroll
        for (int i = 0; i < NH * K / 8 / 256; i++) dst[tid + i * 256] = src[tid + i * 256];
    }
    __syncthreads();
#pragma unroll
    for (int tt = 0; tt < 2; tt++) {
        int tile = mg * 8 + wid + tt * 4;
        int m0 = tile * 16;
        bf16x8 af[KT];
#pragma unroll
        for (int kt = 0; kt < KT; kt++)
            af[kt] = *(const bf16x8*)(X + (size_t)(m0 + ln) * K + kt * 32 + q * 8);
        for (int nt = 0; nt < NTL; nt++) {
            f32x4 acc = {0.f, 0.f, 0.f, 0.f};
#pragma unroll
            for (int kt = 0; kt < KT; kt++) {
                bf16x8 bfr = *(const bf16x8*)&wl[((nt * KT + kt) * 64 + lane) * 8];
                acc = mfma16(af[kt], bfr, acc);
            }
            int g = half * NH + nt * 16 + ln;
            float bv = bias[g];
#pragma unroll
            for (int r = 0; r < 4; r++) {
                int m = m0 + q * 4 + r;
                out[(size_t)m * N + g] = f2b(acc[r] + bv);
            }
        }
    }
}

// ---------------------------------------------------------------------------
// Recurrent GRU kernel. One WG per 16 batch elems (grid 16). Whh held
// register-resident as packed B-fragments; h circulates via LDS.
//   gh = h @ Whh.T ; r=sig(ir+hr+bhr) z=sig(iz+hz+bhz) n=tanh(in+r*(hn+bhn))
//   h' = (1-z)n + z h
// ---------------------------------------------------------------------------
template <int H, bool GI_CONST, bool WRITE_SEQ>
__global__ __launch_bounds__((H == 256) ? 512 : 256) void rec_kernel(
    const u16* __restrict__ gi,     // [steps*256][3H] bf16 (if !GI_CONST)
    const float* __restrict__ gic,  // [256][3H] f32    (if GI_CONST)
    const u16* __restrict__ Wp,     // packed Whh frags
    const float* __restrict__ bhh,  // [3H]
    float* __restrict__ hstate,     // [256][H] f32 (carried across chunks)
    u16* __restrict__ hseq,         // [steps*256][H] bf16 (if WRITE_SEQ)
    int steps) {
    constexpr int NW = (H == 256) ? 8 : 4;
    constexpr int NT = NW * 64;
    constexpr int G3 = 3 * H;
    constexpr int KT = H / 32;
    constexpr int NTW = (G3 / 16) / NW;  // = 6
    __shared__ u16 h_buf[16][H + 8];
    __shared__ float gh2[16][G3 + 4];
    __shared__ u16 gi16[GI_CONST ? 8 : 16 * G3];
    __shared__ float gif[GI_CONST ? 16 * G3 : 8];
    __shared__ float bhh_s[G3];

    int tid = threadIdx.x, wid = tid >> 6, lane = tid & 63, q = lane >> 4, ln = lane & 15;
    int b0 = blockIdx.x * 16;

    // register-resident weight fragments
    bf16x8 wf[NTW][KT];
    const bf16x8* wpv = (const bf16x8*)Wp;
#pragma unroll
    for (int i = 0; i < NTW; i++) {
        int nt = wid * NTW + i;
#pragma unroll
        for (int kt = 0; kt < KT; kt++) wf[i][kt] = wpv[(nt * KT + kt) * 64 + lane];
    }
    for (int idx = tid; idx < 16 * H; idx += NT) {
        int bb = idx / H, k = idx % H;
        h_buf[bb][k] = f2b(hstate[(size_t)(b0 + bb) * H + k]);
    }
    for (int idx = tid; idx < G3; idx += NT) bhh_s[idx] = bhh[idx];
    if (GI_CONST) {
        for (int idx = tid; idx < 16 * G3; idx += NT) {
            int bb = idx / G3, g = idx % G3;
            gif[idx] = gic[(size_t)(b0 + bb) * G3 + g];
        }
    }
    __syncthreads();

    constexpr int NGI = GI_CONST ? 1 : (16 * G3 / 8 / NT);  // = 3 when used
    for (int t = 0; t < steps; t++) {
        bf16x8 greg[NGI];
        if (!GI_CONST) {
            const bf16x8* src = (const bf16x8*)(gi + (size_t)(t * 256 + b0) * G3);
#pragma unroll
            for (int i = 0; i < NGI; i++) greg[i] = src[tid + i * NT];
        }
        f32x4 acc[NTW];
#pragma unroll
        for (int i = 0; i < NTW; i++) acc[i] = (f32x4){0.f, 0.f, 0.f, 0.f};
#pragma unroll
        for (int kh = 0; kh < KT / 2; kh++) {  // 2 A-frags live at a time (VGPR cap)
            bf16x8 af[2];
#pragma unroll
            for (int x = 0; x < 2; x++)
                af[x] = *(const bf16x8*)&h_buf[ln][(kh * 2 + x) * 32 + q * 8];
#pragma unroll
            for (int i = 0; i < NTW; i++)
#pragma unroll
                for (int x = 0; x < 2; x++) acc[i] = mfma16(af[x], wf[i][kh * 2 + x], acc[i]);
        }
        if (!GI_CONST) {
#pragma unroll
            for (int i = 0; i < NGI; i++) ((bf16x8*)gi16)[tid + i * NT] = greg[i];
        }
#pragma unroll
        for (int i = 0; i < NTW; i++) {
            int g = (wid * NTW + i) * 16 + ln;
#pragma unroll
            for (int r = 0; r < 4; r++) gh2[q * 4 + r][g] = acc[i][r];
        }
        __syncthreads();

        // recombine: thread -> batch bb, strided k to stay bank-friendly
        constexpr int TPB = NT / 16;
        int bb = tid / TPB, k0 = tid % TPB;
#pragma unroll
        for (int j = 0; j < H / TPB; j++) {
            int k = k0 + TPB * j;
            float ir, iz, in_;
            if (GI_CONST) {
                ir = gif[bb * G3 + k];
                iz = gif[bb * G3 + H + k];
                in_ = gif[bb * G3 + 2 * H + k];
            } else {
                ir = b2f(gi16[bb * G3 + k]);
                iz = b2f(gi16[bb * G3 + H + k]);
                in_ = b2f(gi16[bb * G3 + 2 * H + k]);
            }
            float hr = gh2[bb][k] + bhh_s[k];
            float hz = gh2[bb][H + k] + bhh_s[H + k];
            float hn = gh2[bb][2 * H + k] + bhh_s[2 * H + k];
            float rr = 1.f / (1.f + __expf(-(ir + hr)));
            float zz = 1.f / (1.f + __expf(-(iz + hz)));
            float e2 = __expf(2.f * (in_ + rr * hn));
            float nn = (e2 - 1.f) / (e2 + 1.f);
            float ho = b2f(h_buf[bb][k]);
            float hv = (1.f - zz) * nn + zz * ho;
            u16 hb = f2b(hv);
            h_buf[bb][k] = hb;
            if (WRITE_SEQ) hseq[(size_t)(t * 256 + b0 + bb) * H + k] = hb;
        }
        __syncthreads();
    }
    for (int idx = tid; idx < 16 * H; idx += NT) {
        int bb = idx / H, k = idx % H;
        hstate[(size_t)(b0 + bb) * H + k] = b2f(h_buf[bb][k]);
    }
}

// ---------------------------------------------------------------------------
// latent = st2 @ l1_W.T + l1_b  (-> d_out[0:16384]) ; gi1_dec = latent @ d1_Wih.T + d1_bih
// ---------------------------------------------------------------------------
__global__ __launch_bounds__(128) void latent_kernel(const float* __restrict__ st2,
                                                     const float* __restrict__ l1W,
                                                     const float* __restrict__ l1b,
                                                     const float* __restrict__ d1Wih,
                                                     const float* __restrict__ d1bih,
                                                     float* __restrict__ dout,
                                                     float* __restrict__ gi1dec) {
    __shared__ float hv[128], lat[64];
    int b = blockIdx.x, tid = threadIdx.x;
    hv[tid] = st2[(size_t)b * 128 + tid];
    __syncthreads();
    if (tid < 64) {
        float s = l1b[tid];
        for (int k = 0; k < 128; k++) s += l1W[tid * 128 + k] * hv[k];
        dout[b * 64 + tid] = s;
        lat[tid] = s;
    }
    __syncthreads();
    for (int g = tid; g < 384; g += 128) {
        float s = d1bih[g];
        for (int k = 0; k < 64; k++) s += d1Wih[g * 64 + k] * lat[k];
        gi1dec[(size_t)b * 384 + g] = s;
    }
}

// ---------------------------------------------------------------------------
// loss chunk: recon = h2d @ l2_W.T + l2_b ; accumulate mean((recon-emb)^2)
// grid 512 x 256thr, 1 M-tile(16) per wave.
// ---------------------------------------------------------------------------
__global__ __launch_bounds__(256) void loss_kernel(const u16* __restrict__ h2d,
                                                   const u16* __restrict__ Wp,
                                                   const float* __restrict__ l2b,
                                                   const u16* __restrict__ embc,
                                                   float* __restrict__ loss) {
    int tid = threadIdx.x, wid = tid >> 6, lane = tid & 63, q = lane >> 4, ln = lane & 15;
    int tile = blockIdx.x * 4 + wid;
    int m0 = tile * 16;
    bf16x8 af[8];
#pragma unroll
    for (int kt = 0; kt < 8; kt++)
        af[kt] = *(const bf16x8*)(h2d + (size_t)(m0 + ln) * 256 + kt * 32 + q * 8);
    float ls = 0.f;
#pragma unroll
    for (int nt = 0; nt < 8; nt++) {
        f32x4 acc = {0.f, 0.f, 0.f, 0.f};
#pragma unroll
        for (int kt = 0; kt < 8; kt++) {
            bf16x8 bfr = *(const bf16x8*)(Wp + ((size_t)(nt * 8 + kt) * 64 + lane) * 8);
            acc = mfma16(af[kt], bfr, acc);
        }
        int g = nt * 16 + ln;
        float bv = l2b[g];
#pragma unroll
        for (int r = 0; r < 4; r++) {
            int m = m0 + q * 4 + r;
            float rec = acc[r] + bv;
            float ev = b2f(embc[(size_t)m * 128 + g]);
            float d = rec - ev;
            ls += d * d;
        }
    }
    __shared__ float red[256];
    red[tid] = ls;
    __syncthreads();
    for (int s = 128; s > 0; s >>= 1) {
        if (tid < s) red[tid] += red[tid + s];
        __syncthreads();
    }
    if (tid == 0) atomicAdd(loss, red[0] * (1.f / 16777216.f));
}

// ---------------------------------------------------------------------------
extern "C" void kernel_launch(void* const* d_in, const int* in_sizes, int n_in,
                              void* d_out, int out_size, void* d_ws, size_t ws_size,
                              hipStream_t stream) {
    (void)in_sizes; (void)n_in; (void)out_size; (void)ws_size;
    const int*   tok   = (const int*)d_in[0];
    const float* pw    = (const float*)d_in[1];
    const float* sw    = (const float*)d_in[2];
    const float* e1Wih = (const float*)d_in[3];
    const float* e1Whh = (const float*)d_in[4];
    const float* e1bih = (const float*)d_in[5];
    const float* e1bhh = (const float*)d_in[6];
    const float* e2Wih = (const float*)d_in[7];
    const float* e2Whh = (const float*)d_in[8];
    const float* e2bih = (const float*)d_in[9];
    const float* e2bhh = (const float*)d_in[10];
    const float* l1W   = (const float*)d_in[11];
    const float* l1b   = (const float*)d_in[12];
    const float* d1Wih = (const float*)d_in[13];
    const float* d1Whh = (const float*)d_in[14];
    const float* d1bih = (const float*)d_in[15];
    const float* d1bhh = (const float*)d_in[16];
    const float* d2Wih = (const float*)d_in[17];
    const float* d2Whh = (const float*)d_in[18];
    const float* d2bih = (const float*)d_in[19];
    const float* d2bhh = (const float*)d_in[20];
    const float* l2W   = (const float*)d_in[21];
    const float* l2b   = (const float*)d_in[22];
    float* dout = (float*)d_out;

    char* base = (char*)d_ws;
    size_t o = 0;
    auto alloc = [&](size_t bytes) { size_t r = o; o += (bytes + 255) & ~(size_t)255; return r; };
    u16* e1Wih_p = (u16*)(base + alloc(48 * 4 * 512 * 2));   // [768][128]
    u16* e1Whh_p = (u16*)(base + alloc(48 * 8 * 512 * 2));   // [768][256]
    u16* e2Wih_p = (u16*)(base + alloc(24 * 8 * 512 * 2));   // [384][256]
    u16* e2Whh_p = (u16*)(base + alloc(24 * 4 * 512 * 2));   // [384][128]
    u16* d1Whh_p = (u16*)(base + alloc(24 * 4 * 512 * 2));   // [384][128]
    u16* d2Wih_p = (u16*)(base + alloc(48 * 4 * 512 * 2));   // [768][128]
    u16* d2Whh_p = (u16*)(base + alloc(48 * 8 * 512 * 2));   // [768][256]
    u16* l2W_p   = (u16*)(base + alloc(8 * 8 * 512 * 2));    // [128][256]
    u16* emb_p   = (u16*)(base + alloc((size_t)131072 * 128 * 2));
    u16* giA     = (u16*)(base + alloc((size_t)MCH * 768 * 2));
    u16* giB     = (u16*)(base + alloc((size_t)MCH * 384 * 2));
    u16* h1chunk = (u16*)(base + alloc((size_t)MCH * 256 * 2));  // also d1's [MCH][128]
    u16* h2chunk = (u16*)(base + alloc((size_t)MCH * 256 * 2));
    float* st1 = (float*)(base + alloc(256 * 256 * 4));
    float* st2 = (float*)(base + alloc(256 * 128 * 4));
    float* st3 = (float*)(base + alloc(256 * 128 * 4));
    float* st4 = (float*)(base + alloc(256 * 256 * 4));
    float* gi1dec = (float*)(base + alloc(256 * 384 * 4));

    // pack weights into MFMA B-fragment order (re-done every call; ws is poisoned)
    pack_kernel<<<192, 64, 0, stream>>>(e1Wih, e1Wih_p, 128);
    pack_kernel<<<384, 64, 0, stream>>>(e1Whh, e1Whh_p, 256);
    pack_kernel<<<192, 64, 0, stream>>>(e2Wih, e2Wih_p, 256);
    pack_kernel<<<96, 64, 0, stream>>>(e2Whh, e2Whh_p, 128);
    pack_kernel<<<96, 64, 0, stream>>>(d1Whh, d1Whh_p, 128);
    pack_kernel<<<192, 64, 0, stream>>>(d2Wih, d2Wih_p, 128);
    pack_kernel<<<384, 64, 0, stream>>>(d2Whh, d2Whh_p, 256);
    pack_kernel<<<64, 64, 0, stream>>>(l2W, l2W_p, 256);

    zero_kernel<<<769, 256, 0, stream>>>(st1, dout + 16384);  // st1..st4 contiguous
    embed_kernel<<<131072, 128, 0, stream>>>(tok, pw, sw, emb_p);

    // encoder
    for (int c = 0; c < NCH; c++) {
        const u16* embc = emb_p + (size_t)c * MCH * 128;
        gemm_kernel<128, 768><<<512, 256, 0, stream>>>(embc, e1Wih_p, e1bih, giA);
        rec_kernel<256, false, true><<<16, 512, 0, stream>>>(giA, nullptr, e1Whh_p, e1bhh,
                                                             st1, h1chunk, CH);
        gemm_kernel<256, 384><<<512, 256, 0, stream>>>(h1chunk, e2Wih_p, e2bih, giB);
        rec_kernel<128, false, false><<<16, 256, 0, stream>>>(giB, nullptr, e2Whh_p, e2bhh,
                                                              st2, nullptr, CH);
    }

    latent_kernel<<<256, 128, 0, stream>>>(st2, l1W, l1b, d1Wih, d1bih, dout, gi1dec);

    // decoder
    for (int c = 0; c < NCH; c++) {
        const u16* embc = emb_p + (size_t)c * MCH * 128;
        rec_kernel<128, true, true><<<16, 256, 0, stream>>>(nullptr, gi1dec, d1Whh_p, d1bhh,
                                                            st3, h1chunk, CH);
        gemm_kernel<128, 768><<<512, 256, 0, stream>>>(h1chunk, d2Wih_p, d2bih, giA);
        rec_kernel<256, false, true><<<16, 512, 0, stream>>>(giA, nullptr, d2Whh_p, d2bhh,
                                                             st4, h2chunk, CH);
        loss_kernel<<<512, 256, 0, stream>>>(h2chunk, l2W_p, l2b, embc, dout + 16384);
    }
}

// Round 2
// 3028.940 us; speedup vs baseline: 2.0104x; 2.0104x over previous
//
#include <hip/hip_runtime.h>
#include <cstddef>

typedef unsigned short u16;
typedef __bf16 bf16x8 __attribute__((ext_vector_type(8)));
typedef float f32x4 __attribute__((ext_vector_type(4)));

__device__ __forceinline__ u16 f2b(float f) {
    unsigned u = __float_as_uint(f);
    u += 0x7fffu + ((u >> 16) & 1u);          // round-to-nearest-even
    return (u16)(u >> 16);
}
__device__ __forceinline__ float b2f(u16 h) { return __uint_as_float(((unsigned)h) << 16); }

__device__ __forceinline__ f32x4 mfma16(bf16x8 a, bf16x8 b, f32x4 c) {
    return __builtin_amdgcn_mfma_f32_16x16x32_bf16(a, b, c, 0, 0, 0);
}

// barrier WITHOUT vmcnt drain: stores/prefetch loads stay in flight.
__device__ __forceinline__ void bar_lds() {
    asm volatile("s_waitcnt lgkmcnt(0)\n\ts_barrier" ::: "memory");
}

// ---------------------------------------------------------------------------
// B=256, S=512, D=128, H=256, HH=128, L=64.  chunk = 128 steps, 4 chunks.
#define CH   128
#define NCH  4
#define MCH  (CH * 256)   // rows per chunk = 32768

// ---------------------------------------------------------------------------
// pack: W [N][K] f32  ->  MFMA B-fragments bf16, frag f=(nt*KT+kt): 64 lanes x 8
//   B[k][n] = W[n][k],  n = nt*16 + (lane&15),  k = kt*32 + (lane>>4)*8 + j
// ---------------------------------------------------------------------------
__global__ __launch_bounds__(64) void pack_kernel(const float* __restrict__ W,
                                                  u16* __restrict__ out, int K) {
    int f = blockIdx.x, lane = threadIdx.x, q = lane >> 4, ln = lane & 15;
    int KT = K / 32;
    int nt = f / KT, kt = f % KT;
    int n = nt * 16 + ln;
    int kb = kt * 32 + q * 8;
#pragma unroll
    for (int j = 0; j < 8; j++)
        out[((size_t)f * 64 + lane) * 8 + j] = f2b(W[(size_t)n * K + kb + j]);
}

// ---------------------------------------------------------------------------
__global__ void zero_kernel(float* __restrict__ st, float* __restrict__ lossslot) {
    int i = blockIdx.x * 256 + threadIdx.x;
    if (i < 196608) st[i] = 0.f;
    if (i == 0) *lossslot = 0.f;
}

// emb[row=t*256+b][d] = path[tok0][d] + sys[tok1][d]   (bf16). 16 rows/block.
__global__ __launch_bounds__(256) void embed_kernel(const int* __restrict__ tok,
                                                    const float* __restrict__ pw,
                                                    const float* __restrict__ sw,
                                                    u16* __restrict__ emb) {
    int col = threadIdx.x & 127;
    int half = threadIdx.x >> 7;
    int rbase = blockIdx.x * 16;
#pragma unroll
    for (int i = 0; i < 8; i++) {
        int r = rbase + i * 2 + half;   // row = t*256 + b
        int b = r & 255, t = r >> 8;
        const int* tp = tok + ((size_t)b * 512 + t) * 2;
        float v = pw[(size_t)tp[0] * 128 + col] + sw[(size_t)tp[1] * 128 + col];
        emb[(size_t)r * 128 + col] = f2b(v);
    }
}

// ---------------------------------------------------------------------------
// big GEMM: out[M=32768][N] = X[M][K](bf16) @ W.T + bias, W pre-packed frags.
// ---------------------------------------------------------------------------
template <int K, int N>
__global__ __launch_bounds__(256) void gemm_kernel(const u16* __restrict__ X,
                                                   const u16* __restrict__ Wp,
                                                   const float* __restrict__ bias,
                                                   u16* __restrict__ out) {
    constexpr int NH = N / 2, KT = K / 32, NTL = NH / 16;
    __shared__ u16 wl[NH * K];
    int tid = threadIdx.x, wid = tid >> 6, lane = tid & 63, q = lane >> 4, ln = lane & 15;
    int half = blockIdx.x & 1, mg = blockIdx.x >> 1;
    {
        const bf16x8* src = (const bf16x8*)(Wp + (size_t)half * NH * K);
        bf16x8* dst = (bf16x8*)wl;
#pragma unroll
        for (int i = 0; i < NH * K / 8 / 256; i++) dst[tid + i * 256] = src[tid + i * 256];
    }
    __syncthreads();
#pragma unroll
    for (int tt = 0; tt < 2; tt++) {
        int tile = mg * 8 + wid + tt * 4;
        int m0 = tile * 16;
        bf16x8 af[KT];
#pragma unroll
        for (int kt = 0; kt < KT; kt++)
            af[kt] = *(const bf16x8*)(X + (size_t)(m0 + ln) * K + kt * 32 + q * 8);
        for (int nt = 0; nt < NTL; nt++) {
            f32x4 acc = {0.f, 0.f, 0.f, 0.f};
#pragma unroll
            for (int kt = 0; kt < KT; kt++) {
                bf16x8 bfr = *(const bf16x8*)&wl[((nt * KT + kt) * 64 + lane) * 8];
                acc = mfma16(af[kt], bfr, acc);
            }
            int g = half * NH + nt * 16 + ln;
            float bv = bias[g];
#pragma unroll
            for (int r = 0; r < 4; r++) {
                int m = m0 + q * 4 + r;
                out[(size_t)m * N + g] = f2b(acc[r] + bv);
            }
        }
    }
}

// ---------------------------------------------------------------------------
// Recurrent GRU kernel. BPG batch elems per WG, grid = 256/BPG, 512 threads.
// Whh register/AGPR-resident as packed B-fragments; h circulates via LDS.
// gi prefetched one step ahead into registers; barriers don't drain vmcnt.
// ---------------------------------------------------------------------------
template <int H, int BPG, bool GI_CONST, bool WRITE_SEQ>
__global__ __launch_bounds__(512) void rec_kernel(
    const u16* __restrict__ gi,     // [steps*256][3H] bf16 (if !GI_CONST)
    const float* __restrict__ gic,  // [256][3H] f32    (if GI_CONST)
    const u16* __restrict__ Wp,     // packed Whh frags
    const float* __restrict__ bhh,  // [3H]
    float* __restrict__ hstate,     // [256][H] f32 (carried across chunks)
    u16* __restrict__ hseq,         // [steps*256][H] bf16 (if WRITE_SEQ)
    int steps) {
    constexpr int NT = 512;
    constexpr int G3 = 3 * H;
    constexpr int KT = H / 32;
    constexpr int NTW = (G3 / 16) / 8;      // N-tiles per wave (6 or 3)
    constexpr int NLD = BPG * G3 / 8;       // bf16x8 gi loads per step
    constexpr int TPB = NT / BPG;           // recombine threads per batch
    __shared__ u16 h_buf[16][H + 8];
    __shared__ float gh2[BPG][G3 + 4];
    __shared__ u16 gi16[GI_CONST ? 8 : NLD * 8];
    __shared__ float gif[GI_CONST ? BPG * G3 : 8];
    __shared__ float bhh_s[G3];

    int tid = threadIdx.x, wid = tid >> 6, lane = tid & 63, q = lane >> 4, ln = lane & 15;
    int b0 = blockIdx.x * BPG;

    // register-resident weight fragments (per-wave N-slice)
    bf16x8 wf[NTW][KT];
    const bf16x8* wpv = (const bf16x8*)Wp;
#pragma unroll
    for (int i = 0; i < NTW; i++) {
        int nt = wid * NTW + i;
#pragma unroll
        for (int kt = 0; kt < KT; kt++) wf[i][kt] = wpv[(nt * KT + kt) * 64 + lane];
    }
    // init h (rows >= BPG stay exactly zero; they feed padded MFMA rows)
    for (int idx = tid; idx < 16 * H; idx += NT) {
        int bb = idx / H, k = idx % H;
        float v = (bb < BPG) ? hstate[(size_t)(b0 + bb) * H + k] : 0.f;
        h_buf[bb][k] = f2b(v);
    }
    for (int idx = tid; idx < G3; idx += NT) bhh_s[idx] = bhh[idx];
    if (GI_CONST) {
        for (int idx = tid; idx < BPG * G3; idx += NT) {
            int bb = idx / G3, g = idx % G3;
            gif[idx] = gic[(size_t)(b0 + bb) * G3 + g];
        }
    }
    // prefetch gi for step 0
    bf16x8 greg;
    const bool ldact = (!GI_CONST) && (tid < NLD);
    if (ldact) greg = ((const bf16x8*)(gi + (size_t)b0 * G3))[tid];
    __syncthreads();

    for (int t = 0; t < steps; t++) {
        // ---- gh = h @ Whh.T (MFMA) ----
        f32x4 acc[NTW];
#pragma unroll
        for (int i = 0; i < NTW; i++) acc[i] = (f32x4){0.f, 0.f, 0.f, 0.f};
#pragma unroll
        for (int kh = 0; kh < KT / 2; kh++) {
            bf16x8 af[2];
#pragma unroll
            for (int x = 0; x < 2; x++)
                af[x] = *(const bf16x8*)&h_buf[ln][(kh * 2 + x) * 32 + q * 8];
#pragma unroll
            for (int i = 0; i < NTW; i++)
#pragma unroll
                for (int x = 0; x < 2; x++) acc[i] = mfma16(af[x], wf[i][kh * 2 + x], acc[i]);
        }
        // ---- stage gi(t) to LDS, prefetch gi(t+1) ----
        if (ldact) {
            ((bf16x8*)gi16)[tid] = greg;
            if (t + 1 < steps)
                greg = ((const bf16x8*)(gi + (size_t)((t + 1) * 256 + b0) * G3))[tid];
        }
        // ---- acc -> gh2 (only real batch rows: row = q*4+r, rows 0..BPG-1) ----
        if (q == 0) {
#pragma unroll
            for (int i = 0; i < NTW; i++) {
                int g = (wid * NTW + i) * 16 + ln;
#pragma unroll
                for (int r = 0; r < 4; r++)
                    if (r < BPG) gh2[r][g] = acc[i][r];
            }
        }
        bar_lds();

        // ---- recombine ----
        int bb = tid / TPB, k0 = tid % TPB;
#pragma unroll
        for (int j = 0; j < H / TPB; j++) {
            int k = k0 + TPB * j;
            float ir, iz, in_;
            if (GI_CONST) {
                ir = gif[bb * G3 + k];
                iz = gif[bb * G3 + H + k];
                in_ = gif[bb * G3 + 2 * H + k];
            } else {
                ir = b2f(gi16[bb * G3 + k]);
                iz = b2f(gi16[bb * G3 + H + k]);
                in_ = b2f(gi16[bb * G3 + 2 * H + k]);
            }
            float hr = gh2[bb][k] + bhh_s[k];
            float hz = gh2[bb][H + k] + bhh_s[H + k];
            float hn = gh2[bb][2 * H + k] + bhh_s[2 * H + k];
            float rr = 1.f / (1.f + __expf(-(ir + hr)));
            float zz = 1.f / (1.f + __expf(-(iz + hz)));
            float e2 = __expf(2.f * (in_ + rr * hn));
            float nn = (e2 - 1.f) / (e2 + 1.f);
            float ho = b2f(h_buf[bb][k]);
            float hv = (1.f - zz) * nn + zz * ho;
            u16 hb = f2b(hv);
            h_buf[bb][k] = hb;
            if (WRITE_SEQ) hseq[(size_t)(t * 256 + b0 + bb) * H + k] = hb;
            if (t == steps - 1) hstate[(size_t)(b0 + bb) * H + k] = hv;
        }
        bar_lds();
    }
}

// ---------------------------------------------------------------------------
// latent = st2 @ l1_W.T + l1_b  (-> d_out[0:16384]) ; gi1_dec = latent @ d1_Wih.T + d1_bih
// ---------------------------------------------------------------------------
__global__ __launch_bounds__(128) void latent_kernel(const float* __restrict__ st2,
                                                     const float* __restrict__ l1W,
                                                     const float* __restrict__ l1b,
                                                     const float* __restrict__ d1Wih,
                                                     const float* __restrict__ d1bih,
                                                     float* __restrict__ dout,
                                                     float* __restrict__ gi1dec) {
    __shared__ float hv[128], lat[64];
    int b = blockIdx.x, tid = threadIdx.x;
    hv[tid] = st2[(size_t)b * 128 + tid];
    __syncthreads();
    if (tid < 64) {
        float s = l1b[tid];
        for (int k = 0; k < 128; k++) s += l1W[tid * 128 + k] * hv[k];
        dout[b * 64 + tid] = s;
        lat[tid] = s;
    }
    __syncthreads();
    for (int g = tid; g < 384; g += 128) {
        float s = d1bih[g];
        for (int k = 0; k < 64; k++) s += d1Wih[g * 64 + k] * lat[k];
        gi1dec[(size_t)b * 384 + g] = s;
    }
}

// ---------------------------------------------------------------------------
// loss chunk: recon = h2d @ l2_W.T + l2_b ; accumulate mean((recon-emb)^2)
// ---------------------------------------------------------------------------
__global__ __launch_bounds__(256) void loss_kernel(const u16* __restrict__ h2d,
                                                   const u16* __restrict__ Wp,
                                                   const float* __restrict__ l2b,
                                                   const u16* __restrict__ embc,
                                                   float* __restrict__ loss) {
    int tid = threadIdx.x, wid = tid >> 6, lane = tid & 63, q = lane >> 4, ln = lane & 15;
    int tile = blockIdx.x * 4 + wid;
    int m0 = tile * 16;
    bf16x8 af[8];
#pragma unroll
    for (int kt = 0; kt < 8; kt++)
        af[kt] = *(const bf16x8*)(h2d + (size_t)(m0 + ln) * 256 + kt * 32 + q * 8);
    float ls = 0.f;
#pragma unroll
    for (int nt = 0; nt < 8; nt++) {
        f32x4 acc = {0.f, 0.f, 0.f, 0.f};
#pragma unroll
        for (int kt = 0; kt < 8; kt++) {
            bf16x8 bfr = *(const bf16x8*)(Wp + ((size_t)(nt * 8 + kt) * 64 + lane) * 8);
            acc = mfma16(af[kt], bfr, acc);
        }
        int g = nt * 16 + ln;
        float bv = l2b[g];
#pragma unroll
        for (int r = 0; r < 4; r++) {
            int m = m0 + q * 4 + r;
            float rec = acc[r] + bv;
            float ev = b2f(embc[(size_t)m * 128 + g]);
            float d = rec - ev;
            ls += d * d;
        }
    }
    __shared__ float red[256];
    red[tid] = ls;
    __syncthreads();
    for (int s = 128; s > 0; s >>= 1) {
        if (tid < s) red[tid] += red[tid + s];
        __syncthreads();
    }
    if (tid == 0) atomicAdd(loss, red[0] * (1.f / 16777216.f));
}

// ---------------------------------------------------------------------------
extern "C" void kernel_launch(void* const* d_in, const int* in_sizes, int n_in,
                              void* d_out, int out_size, void* d_ws, size_t ws_size,
                              hipStream_t stream) {
    (void)in_sizes; (void)n_in; (void)out_size; (void)ws_size;
    const int*   tok   = (const int*)d_in[0];
    const float* pw    = (const float*)d_in[1];
    const float* sw    = (const float*)d_in[2];
    const float* e1Wih = (const float*)d_in[3];
    const float* e1Whh = (const float*)d_in[4];
    const float* e1bih = (const float*)d_in[5];
    const float* e1bhh = (const float*)d_in[6];
    const float* e2Wih = (const float*)d_in[7];
    const float* e2Whh = (const float*)d_in[8];
    const float* e2bih = (const float*)d_in[9];
    const float* e2bhh = (const float*)d_in[10];
    const float* l1W   = (const float*)d_in[11];
    const float* l1b   = (const float*)d_in[12];
    const float* d1Wih = (const float*)d_in[13];
    const float* d1Whh = (const float*)d_in[14];
    const float* d1bih = (const float*)d_in[15];
    const float* d1bhh = (const float*)d_in[16];
    const float* d2Wih = (const float*)d_in[17];
    const float* d2Whh = (const float*)d_in[18];
    const float* d2bih = (const float*)d_in[19];
    const float* d2bhh = (const float*)d_in[20];
    const float* l2W   = (const float*)d_in[21];
    const float* l2b   = (const float*)d_in[22];
    float* dout = (float*)d_out;

    char* base = (char*)d_ws;
    size_t o = 0;
    auto alloc = [&](size_t bytes) { size_t r = o; o += (bytes + 255) & ~(size_t)255; return r; };
    u16* e1Wih_p = (u16*)(base + alloc(48 * 4 * 512 * 2));   // [768][128]
    u16* e1Whh_p = (u16*)(base + alloc(48 * 8 * 512 * 2));   // [768][256]
    u16* e2Wih_p = (u16*)(base + alloc(24 * 8 * 512 * 2));   // [384][256]
    u16* e2Whh_p = (u16*)(base + alloc(24 * 4 * 512 * 2));   // [384][128]
    u16* d1Whh_p = (u16*)(base + alloc(24 * 4 * 512 * 2));   // [384][128]
    u16* d2Wih_p = (u16*)(base + alloc(48 * 4 * 512 * 2));   // [768][128]
    u16* d2Whh_p = (u16*)(base + alloc(48 * 8 * 512 * 2));   // [768][256]
    u16* l2W_p   = (u16*)(base + alloc(8 * 8 * 512 * 2));    // [128][256]
    u16* emb_p   = (u16*)(base + alloc((size_t)131072 * 128 * 2));
    u16* giA     = (u16*)(base + alloc((size_t)MCH * 768 * 2));
    u16* giB     = (u16*)(base + alloc((size_t)MCH * 384 * 2));
    u16* h1chunk = (u16*)(base + alloc((size_t)MCH * 256 * 2));  // also d1's [MCH][128]
    u16* h2chunk = (u16*)(base + alloc((size_t)MCH * 256 * 2));
    float* st1 = (float*)(base + alloc(256 * 256 * 4));
    float* st2 = (float*)(base + alloc(256 * 128 * 4));
    float* st3 = (float*)(base + alloc(256 * 128 * 4));
    float* st4 = (float*)(base + alloc(256 * 256 * 4));
    float* gi1dec = (float*)(base + alloc(256 * 384 * 4));

    // pack weights into MFMA B-fragment order (re-done every call; ws is poisoned)
    pack_kernel<<<192, 64, 0, stream>>>(e1Wih, e1Wih_p, 128);
    pack_kernel<<<384, 64, 0, stream>>>(e1Whh, e1Whh_p, 256);
    pack_kernel<<<192, 64, 0, stream>>>(e2Wih, e2Wih_p, 256);
    pack_kernel<<<96, 64, 0, stream>>>(e2Whh, e2Whh_p, 128);
    pack_kernel<<<96, 64, 0, stream>>>(d1Whh, d1Whh_p, 128);
    pack_kernel<<<192, 64, 0, stream>>>(d2Wih, d2Wih_p, 128);
    pack_kernel<<<384, 64, 0, stream>>>(d2Whh, d2Whh_p, 256);
    pack_kernel<<<64, 64, 0, stream>>>(l2W, l2W_p, 256);

    zero_kernel<<<769, 256, 0, stream>>>(st1, dout + 16384);  // st1..st4 contiguous
    embed_kernel<<<8192, 256, 0, stream>>>(tok, pw, sw, emb_p);

    // encoder
    for (int c = 0; c < NCH; c++) {
        const u16* embc = emb_p + (size_t)c * MCH * 128;
        gemm_kernel<128, 768><<<512, 256, 0, stream>>>(embc, e1Wih_p, e1bih, giA);
        rec_kernel<256, 4, false, true><<<64, 512, 0, stream>>>(giA, nullptr, e1Whh_p, e1bhh,
                                                                st1, h1chunk, CH);
        gemm_kernel<256, 384><<<512, 256, 0, stream>>>(h1chunk, e2Wih_p, e2bih, giB);
        rec_kernel<128, 4, false, false><<<64, 512, 0, stream>>>(giB, nullptr, e2Whh_p, e2bhh,
                                                                 st2, nullptr, CH);
    }

    latent_kernel<<<256, 128, 0, stream>>>(st2, l1W, l1b, d1Wih, d1bih, dout, gi1dec);

    // decoder
    for (int c = 0; c < NCH; c++) {
        const u16* embc = emb_p + (size_t)c * MCH * 128;
        rec_kernel<128, 4, true, true><<<64, 512, 0, stream>>>(nullptr, gi1dec, d1Whh_p, d1bhh,
                                                               st3, h1chunk, CH);
        gemm_kernel<128, 768><<<512, 256, 0, stream>>>(h1chunk, d2Wih_p, d2bih, giA);
        rec_kernel<256, 4, false, true><<<64, 512, 0, stream>>>(giA, nullptr, d2Whh_p, d2bhh,
                                                                st4, h2chunk, CH);
        loss_kernel<<<512, 256, 0, stream>>>(h2chunk, l2W_p, l2b, embc, dout + 16384);
    }
}